// Round 1
// 1170.919 us; speedup vs baseline: 1.1246x; 1.1246x over previous
//
#include <hip/hip_runtime.h>
#include <cstdint>
#include <cstddef>

typedef __bf16 bf16_t;
typedef __attribute__((ext_vector_type(8))) __bf16 bf16x8;
typedef __attribute__((ext_vector_type(4))) __bf16 bf16x4;
typedef __attribute__((ext_vector_type(4))) float floatx4;

// ---------------------------------------------------------------------------
// async 16B global -> LDS copy (direct-to-LDS DMA, no VGPR round trip).
// LDS dest must be wave-uniform base + lane*16 — our layouts guarantee this.
__device__ __forceinline__ void cp16(const void* g, void* l) {
  __builtin_amdgcn_global_load_lds(
      (const __attribute__((address_space(1))) void*)(uintptr_t)g,
      (__attribute__((address_space(3))) void*)(uintptr_t)l, 16, 0, 0);
}

// stage one 16 KB half-tile (256 rows x 32 k bf16): 2 issues x 512 thr x 16 B.
// p already includes per-thread row (tid>>2) and pre-swizzled k-slot offset.
__device__ __forceinline__ void stage_half(const bf16_t* p, int K, char* dst,
                                           int tid) {
  cp16(p, dst + tid * 16);
  cp16(p + (size_t)128 * K, dst + 8192 + tid * 16);
}

// ---------------------------------------------------------------------------
// x fp32 -> bf16 (vectorized)
__global__ void cvt_to_bf16(const float4* __restrict__ in,
                            bf16x4* __restrict__ out, int n4) {
  int i = blockIdx.x * 256 + threadIdx.x;
  if (i < n4) {
    float4 f = in[i];
    bf16x4 o;
    o[0] = (bf16_t)f.x; o[1] = (bf16_t)f.y; o[2] = (bf16_t)f.z; o[3] = (bf16_t)f.w;
    out[i] = o;
  }
}

// ---------------------------------------------------------------------------
// W^T assembly: Wt[n][k] = bf16(M[k][n] + exp(.5u[k]) * eps[k][n] * exp(.5v[n]))
__global__ void prep_wt(const float* __restrict__ M, const float* __restrict__ u,
                        const float* __restrict__ v, const float* __restrict__ eps,
                        bf16_t* __restrict__ Wt, int K, int N) {
  __shared__ float tile[32][33];  // +1 pad: conflict-free transposed read
  const int nb = blockIdx.x * 32, kb = blockIdx.y * 32;
  const int tx = threadIdx.x, ty = threadIdx.y;
  const float sv = __expf(0.5f * v[nb + tx]);
#pragma unroll
  for (int r = 0; r < 4; ++r) {
    const int k = kb + ty + 8 * r;
    const float su = __expf(0.5f * u[k]);
    const size_t idx = (size_t)k * N + nb + tx;
    tile[ty + 8 * r][tx] = M[idx] + su * eps[idx] * sv;
  }
  __syncthreads();
#pragma unroll
  for (int r = 0; r < 4; ++r) {
    const int n = nb + ty + 8 * r;
    Wt[(size_t)n * K + kb + tx] = (bf16_t)tile[tx][ty + 8 * r];
  }
}

__global__ void prep_bias(const float* __restrict__ M, const float* __restrict__ u,
                          const float* __restrict__ v, const float* __restrict__ eps,
                          float* __restrict__ bias, int K, int N) {
  int n = blockIdx.x * 256 + threadIdx.x;
  if (n < N) {
    const size_t idx = (size_t)K * N + n;
    bias[n] = M[idx] + __expf(0.5f * u[K]) * eps[idx] * __expf(0.5f * v[n]);
  }
}

// ---------------------------------------------------------------------------
// 256x256 8-phase bf16 GEMM (T1+T2+T3/T4+T5), C = A[8192,K] @ Bt[N,K]^T + bias.
// 8 waves (2M x 4N), BK=64 split in two kk-halves; LDS 128 KiB double-buffered:
//   buf b at b*65536:  A [kk][256][32]bf16 at +0/+16384, B at +32768/+49152.
// LDS swizzle: slot(bits 5:4) ^= (row>>1)&3 — applied on the global SOURCE for
// staging (linear DMA dest) and on the ds_read address (rule #21, both-sides).
//
// K-tile t (buffer CURB = t&1), 4 phases; region-retire ledger:
//   kk0 regions of cur: last ds_read in ph1 (B kk0 regs loaded in ph0 only)
//   kk1 regions of cur: last ds_read in ph3
//   ph0 stages A-k1(t+1)->nxt, ph1 B-k1(t+1)->nxt  (nxt free since tile t-1)
//   ph2 stages A-k0(t+2)->cur, ph3 B-k0(t+2)->cur  (kk0 retired after ph1)
// end-of-tile: vmcnt(4) — tile t+1 fully landed, t+2's k0 halves in flight.
template <int CURB>
__device__ __forceinline__ void ktile(int t, int NT, int K,
                                      const bf16_t* gA, const bf16_t* gB,
                                      char* lds, int tid, int aoff0, int boff0,
                                      floatx4 (&acc)[8][4]) {
  constexpr int curO = CURB * 65536;
  constexpr int nxtO = (CURB ^ 1) * 65536;
  bf16x8 af[4], bb[4];

  // ---- phase 0: m0-3 x kk0 ----
#pragma unroll
  for (int m = 0; m < 4; ++m)
    af[m] = *(const bf16x8*)(lds + curO + aoff0 + m * 1024);
#pragma unroll
  for (int n = 0; n < 4; ++n)
    bb[n] = *(const bf16x8*)(lds + curO + 32768 + boff0 + n * 1024);
  if (t + 1 < NT)
    stage_half(gA + (size_t)(t + 1) * 64 + 32, K, lds + nxtO + 16384, tid);
  __builtin_amdgcn_s_barrier();
  asm volatile("s_waitcnt lgkmcnt(0)" ::: "memory");
  __builtin_amdgcn_sched_barrier(0);
  __builtin_amdgcn_s_setprio(1);
#pragma unroll
  for (int m = 0; m < 4; ++m)
#pragma unroll
    for (int n = 0; n < 4; ++n)
      acc[m][n] = __builtin_amdgcn_mfma_f32_16x16x32_bf16(af[m], bb[n],
                                                          acc[m][n], 0, 0, 0);
  __builtin_amdgcn_s_setprio(0);
  __builtin_amdgcn_sched_barrier(0);
  __builtin_amdgcn_s_barrier();

  // ---- phase 1: m4-7 x kk0 (B kk0 frags held in regs) ----
#pragma unroll
  for (int m = 0; m < 4; ++m)
    af[m] = *(const bf16x8*)(lds + curO + aoff0 + (m + 4) * 1024);
  if (t + 1 < NT)
    stage_half(gB + (size_t)(t + 1) * 64 + 32, K, lds + nxtO + 49152, tid);
  __builtin_amdgcn_s_barrier();
  asm volatile("s_waitcnt lgkmcnt(0)" ::: "memory");
  __builtin_amdgcn_sched_barrier(0);
  __builtin_amdgcn_s_setprio(1);
#pragma unroll
  for (int m = 0; m < 4; ++m)
#pragma unroll
    for (int n = 0; n < 4; ++n)
      acc[m + 4][n] = __builtin_amdgcn_mfma_f32_16x16x32_bf16(af[m], bb[n],
                                                              acc[m + 4][n], 0, 0, 0);
  __builtin_amdgcn_s_setprio(0);
  __builtin_amdgcn_sched_barrier(0);
  __builtin_amdgcn_s_barrier();

  // ---- phase 2: m0-3 x kk1; stage t+2 A-k0 into cur (kk0 retired) ----
#pragma unroll
  for (int m = 0; m < 4; ++m)
    af[m] = *(const bf16x8*)(lds + curO + 16384 + aoff0 + m * 1024);
#pragma unroll
  for (int n = 0; n < 4; ++n)
    bb[n] = *(const bf16x8*)(lds + curO + 49152 + boff0 + n * 1024);
  if (t + 2 < NT)
    stage_half(gA + (size_t)(t + 2) * 64, K, lds + curO, tid);
  __builtin_amdgcn_s_barrier();
  asm volatile("s_waitcnt lgkmcnt(0)" ::: "memory");
  __builtin_amdgcn_sched_barrier(0);
  __builtin_amdgcn_s_setprio(1);
#pragma unroll
  for (int m = 0; m < 4; ++m)
#pragma unroll
    for (int n = 0; n < 4; ++n)
      acc[m][n] = __builtin_amdgcn_mfma_f32_16x16x32_bf16(af[m], bb[n],
                                                          acc[m][n], 0, 0, 0);
  __builtin_amdgcn_s_setprio(0);
  __builtin_amdgcn_sched_barrier(0);
  __builtin_amdgcn_s_barrier();

  // ---- phase 3: m4-7 x kk1; stage t+2 B-k0 into cur ----
#pragma unroll
  for (int m = 0; m < 4; ++m)
    af[m] = *(const bf16x8*)(lds + curO + 16384 + aoff0 + (m + 4) * 1024);
  if (t + 2 < NT)
    stage_half(gB + (size_t)(t + 2) * 64, K, lds + curO + 32768, tid);
  __builtin_amdgcn_s_barrier();
  asm volatile("s_waitcnt lgkmcnt(0)" ::: "memory");
  __builtin_amdgcn_sched_barrier(0);
  __builtin_amdgcn_s_setprio(1);
#pragma unroll
  for (int m = 0; m < 4; ++m)
#pragma unroll
    for (int n = 0; n < 4; ++n)
      acc[m + 4][n] = __builtin_amdgcn_mfma_f32_16x16x32_bf16(af[m], bb[n],
                                                              acc[m + 4][n], 0, 0, 0);
  __builtin_amdgcn_s_setprio(0);
  __builtin_amdgcn_sched_barrier(0);
  // counted vmcnt: never 0 in steady state (T4). 4 loads = t+2's k0 halves.
  if (t + 2 < NT) {
    asm volatile("s_waitcnt vmcnt(4)" ::: "memory");
  } else if (t + 1 < NT) {
    asm volatile("s_waitcnt vmcnt(0)" ::: "memory");
  }
  __builtin_amdgcn_s_barrier();
}

template <int EPI>
__global__ __launch_bounds__(512, 2) void gemm256(
    const bf16_t* __restrict__ A, const bf16_t* __restrict__ Bt,
    const float* __restrict__ bias, void* __restrict__ Cout, int N, int K) {
  extern __shared__ char lds[];
  const int tid = threadIdx.x;
  const int lane = tid & 63;
  const int wave = tid >> 6;
  const int wm = (wave >> 2) * 128;   // 2 M-waves
  const int wn = (wave & 3) * 64;     // 4 N-waves
  const int l15 = lane & 15;
  // swizzled ds_read slot: (logical slot lane>>4) ^ ((row>>1)&3), row parity
  // from lane&15 (frag row bases are multiples of 16).
  const int kqs = ((lane >> 4) ^ ((lane >> 1) & 3)) << 4;
  const int aoff0 = (wm + l15) * 64 + kqs;
  const int bofB0 = (wn + l15) * 64 + kqs;

  // XCD-aware bijective swizzle (nwg % 8 == 0 for all our grids)
  const int gx = gridDim.x;
  int id = blockIdx.y * gx + blockIdx.x;
  const int cpx = (gx * (int)gridDim.y) >> 3;
  id = (id & 7) * cpx + (id >> 3);
  const int bm = (id / gx) * 256;
  const int bn = (id % gx) * 256;

  // staging source: row tid>>2 (+128 for 2nd issue), inverse-swizzled k-slot
  const int srow = tid >> 2;
  const int ss8 = ((tid & 3) ^ ((tid >> 3) & 3)) * 8;
  const bf16_t* gA = A + (size_t)(bm + srow) * K + ss8;
  const bf16_t* gB = Bt + (size_t)(bn + srow) * K + ss8;

  const int NT = K >> 6;  // 32 or 64, always even, >= 2

  floatx4 acc[8][4] = {};

  // ---- prologue: tile0 (4 halves) + tile1 k0 halves; vmcnt(4) leaves t1-k0
  stage_half(gA, K, lds + 0, tid);            // t0 A k0
  stage_half(gA + 32, K, lds + 16384, tid);   // t0 A k1
  stage_half(gB, K, lds + 32768, tid);        // t0 B k0
  stage_half(gB + 32, K, lds + 49152, tid);   // t0 B k1
  stage_half(gA + 64, K, lds + 65536, tid);           // t1 A k0
  stage_half(gB + 64, K, lds + 65536 + 32768, tid);   // t1 B k0
  asm volatile("s_waitcnt vmcnt(4)" ::: "memory");
  __builtin_amdgcn_s_barrier();

  for (int t = 0; t < NT; t += 2) {
    ktile<0>(t, NT, K, gA, gB, lds, tid, aoff0, bofB0, acc);
    ktile<1>(t + 1, NT, K, gA, gB, lds, tid, aoff0, bofB0, acc);
  }

  // epilogue: C/D layout col = lane&15, row = (lane>>4)*4 + reg [m89-verified]
  const int kq4 = lane >> 4;
  const int col0 = bn + wn + l15;
  const int row0 = bm + wm + kq4 * 4;
#pragma unroll
  for (int j = 0; j < 4; ++j) {
    const float bj = bias[col0 + j * 16];
#pragma unroll
    for (int m = 0; m < 8; ++m) {
#pragma unroll
      for (int r = 0; r < 4; ++r) {
        float v = acc[m][j][r] + bj;
        const size_t idx = (size_t)(row0 + m * 16 + r) * N + (col0 + j * 16);
        if (EPI == 0) {
          v = v > 0.f ? v : 0.f;
          ((bf16_t*)Cout)[idx] = (bf16_t)v;
        } else {
          ((float*)Cout)[idx] = v;
        }
      }
    }
  }
}

// ---------------------------------------------------------------------------
extern "C" void kernel_launch(void* const* d_in, const int* in_sizes, int n_in,
                              void* d_out, int out_size, void* d_ws, size_t ws_size,
                              hipStream_t stream) {
  const float* x = (const float*)d_in[0];
  const float *Mm[4], *uu[4], *vv[4], *ee[4];
  for (int i = 0; i < 4; ++i) {
    Mm[i] = (const float*)d_in[1 + 4 * i];
    uu[i] = (const float*)d_in[2 + 4 * i];
    vv[i] = (const float*)d_in[3 + 4 * i];
    ee[i] = (const float*)d_in[4 + 4 * i];
  }

  // workspace layout (≈224 MiB):
  //   Wt0 [4096,2048] bf16 | Wt1 [4096,4096] | Wt2 [4096,4096] | Wt3 [2048,4096]
  //   bias0..3 fp32 | hA (8192x4096 bf16) | hB (8192x4096 bf16)
  char* ws = (char*)d_ws;
  bf16_t* Wt0 = (bf16_t*)ws;
  bf16_t* Wt1 = (bf16_t*)(ws + 16777216);
  bf16_t* Wt2 = (bf16_t*)(ws + 16777216 + 33554432);
  bf16_t* Wt3 = (bf16_t*)(ws + 16777216 + 2u * 33554432);
  char* bptr = ws + 2u * 16777216 + 2u * 33554432;
  float* bias0 = (float*)(bptr);
  float* bias1 = (float*)(bptr + 16384);
  float* bias2 = (float*)(bptr + 32768);
  float* bias3 = (float*)(bptr + 49152);
  char* act = bptr + 65536;
  bf16_t* hA = (bf16_t*)act;
  bf16_t* hB = (bf16_t*)(act + 67108864);
  bf16_t* xb = (bf16_t*)d_out;  // dead until final GEMM overwrites d_out

  static bool attr_set = false;
  if (!attr_set) {
    (void)hipFuncSetAttribute(reinterpret_cast<const void*>(&gemm256<0>),
                              hipFuncAttributeMaxDynamicSharedMemorySize, 131072);
    (void)hipFuncSetAttribute(reinterpret_cast<const void*>(&gemm256<1>),
                              hipFuncAttributeMaxDynamicSharedMemorySize, 131072);
    attr_set = true;
  }

  // --- prep ---
  cvt_to_bf16<<<16384, 256, 0, stream>>>((const float4*)x, (bf16x4*)xb,
                                         8192 * 2048 / 4);
  prep_wt<<<dim3(4096 / 32, 2048 / 32), dim3(32, 8), 0, stream>>>(
      Mm[0], uu[0], vv[0], ee[0], Wt0, 2048, 4096);
  prep_wt<<<dim3(4096 / 32, 4096 / 32), dim3(32, 8), 0, stream>>>(
      Mm[1], uu[1], vv[1], ee[1], Wt1, 4096, 4096);
  prep_wt<<<dim3(4096 / 32, 4096 / 32), dim3(32, 8), 0, stream>>>(
      Mm[2], uu[2], vv[2], ee[2], Wt2, 4096, 4096);
  prep_wt<<<dim3(2048 / 32, 4096 / 32), dim3(32, 8), 0, stream>>>(
      Mm[3], uu[3], vv[3], ee[3], Wt3, 4096, 2048);
  prep_bias<<<16, 256, 0, stream>>>(Mm[0], uu[0], vv[0], ee[0], bias0, 2048, 4096);
  prep_bias<<<16, 256, 0, stream>>>(Mm[1], uu[1], vv[1], ee[1], bias1, 4096, 4096);
  prep_bias<<<16, 256, 0, stream>>>(Mm[2], uu[2], vv[2], ee[2], bias2, 4096, 4096);
  prep_bias<<<8, 256, 0, stream>>>(Mm[3], uu[3], vv[3], ee[3], bias3, 4096, 2048);

  // --- chained GEMMs: 256^2 8-phase ---
  gemm256<0><<<dim3(16, 32), 512, 131072, stream>>>(xb, Wt0, bias0, hA, 4096, 2048);
  gemm256<0><<<dim3(16, 32), 512, 131072, stream>>>(hA, Wt1, bias1, hB, 4096, 4096);
  gemm256<0><<<dim3(16, 32), 512, 131072, stream>>>(hB, Wt2, bias2, hA, 4096, 4096);
  gemm256<1><<<dim3(8, 32), 512, 131072, stream>>>(hA, Wt3, bias3, d_out, 2048, 4096);
}

// Round 2
// 1169.313 us; speedup vs baseline: 1.1262x; 1.0014x over previous
//
#include <hip/hip_runtime.h>
#include <cstdint>
#include <cstddef>

typedef __bf16 bf16_t;
typedef __attribute__((ext_vector_type(8))) __bf16 bf16x8;
typedef __attribute__((ext_vector_type(4))) __bf16 bf16x4;
typedef __attribute__((ext_vector_type(4))) float floatx4;

#define SB0 __builtin_amdgcn_sched_barrier(0)
#define LGKM(N)                                          \
  do {                                                   \
    asm volatile("s_waitcnt lgkmcnt(" #N ")" ::: "memory"); \
    SB0;                                                 \
  } while (0)

// ---------------------------------------------------------------------------
// async 16B global -> LDS copy (direct-to-LDS DMA, no VGPR round trip).
__device__ __forceinline__ void cp16(const void* g, void* l) {
  __builtin_amdgcn_global_load_lds(
      (const __attribute__((address_space(1))) void*)(uintptr_t)g,
      (__attribute__((address_space(3))) void*)(uintptr_t)l, 16, 0, 0);
}

// stage one 16 KB half-tile (256 rows x 32 k bf16): 2 issues x 512 thr x 16 B.
__device__ __forceinline__ void stage_half(const bf16_t* p, int K, char* dst,
                                           int tid) {
  cp16(p, dst + tid * 16);
  cp16(p + (size_t)128 * K, dst + 8192 + tid * 16);
}

// ---------------------------------------------------------------------------
__global__ void cvt_to_bf16(const float4* __restrict__ in,
                            bf16x4* __restrict__ out, int n4) {
  int i = blockIdx.x * 256 + threadIdx.x;
  if (i < n4) {
    float4 f = in[i];
    bf16x4 o;
    o[0] = (bf16_t)f.x; o[1] = (bf16_t)f.y; o[2] = (bf16_t)f.z; o[3] = (bf16_t)f.w;
    out[i] = o;
  }
}

// ---------------------------------------------------------------------------
// W^T assembly: Wt[n][k] = bf16(M[k][n] + exp(.5u[k]) * eps[k][n] * exp(.5v[n]))
__global__ void prep_wt(const float* __restrict__ M, const float* __restrict__ u,
                        const float* __restrict__ v, const float* __restrict__ eps,
                        bf16_t* __restrict__ Wt, int K, int N) {
  __shared__ float tile[32][33];
  const int nb = blockIdx.x * 32, kb = blockIdx.y * 32;
  const int tx = threadIdx.x, ty = threadIdx.y;
  const float sv = __expf(0.5f * v[nb + tx]);
#pragma unroll
  for (int r = 0; r < 4; ++r) {
    const int k = kb + ty + 8 * r;
    const float su = __expf(0.5f * u[k]);
    const size_t idx = (size_t)k * N + nb + tx;
    tile[ty + 8 * r][tx] = M[idx] + su * eps[idx] * sv;
  }
  __syncthreads();
#pragma unroll
  for (int r = 0; r < 4; ++r) {
    const int n = nb + ty + 8 * r;
    Wt[(size_t)n * K + kb + tx] = (bf16_t)tile[tx][ty + 8 * r];
  }
}

// all 4 layers' bias rows in one launch (kills 3 launch gaps)
struct BiasArgs {
  const float* M[4];
  const float* u[4];
  const float* v[4];
  const float* e[4];
  float* b[4];
};
__global__ void prep_bias_all(BiasArgs a) {
  const int bid = blockIdx.x;
  int layer, base;
  if (bid < 16) { layer = 0; base = bid; }
  else if (bid < 32) { layer = 1; base = bid - 16; }
  else if (bid < 48) { layer = 2; base = bid - 32; }
  else { layer = 3; base = bid - 48; }
  const int K = (layer == 0) ? 2048 : 4096;
  const int N = (layer == 3) ? 2048 : 4096;
  const int n = base * 256 + threadIdx.x;
  if (n < N) {
    const size_t idx = (size_t)K * N + n;
    a.b[layer][n] = a.M[layer][idx] +
                    __expf(0.5f * a.u[layer][K]) * a.e[layer][idx] *
                        __expf(0.5f * a.v[layer][n]);
  }
}

// ---------------------------------------------------------------------------
// 256x256 8-phase bf16 GEMM. One barrier per phase + intra-phase counted-lgkm
// ladder: tail ds_reads are serviced under the leading MFMA quads, and waves
// slip within a phase so MFMA and LDS service overlap across waves.
//
// Swapped-operand MFMA: mfma(bb, af, acc) -> lane holds 4 consecutive N-cols
// per acc reg quad (row = lane&15 + m*16, col = (lane>>4)*4 + reg + n*16),
// enabling packed 8B/16B epilogue stores.
//
// WAR/RAW ledger (1 barrier/phase), buffer cur=t&1:
//   ph0 reads cur kk0 (A m0-3 + B): published by tile-end barrier of t-1
//       (vmcnt(4) leaves only t+1-k0 in flight). stage A-k1(t+1)->nxt: that
//       region's last reader was t-1's ph2/ph3 reads, drained at their
//       lgkm(0) before t-1's phase barriers.
//   ph1 reads cur kk0 A m4-7; drains at its lgkm(0) before ph1 barrier.
//       stage B-k1(t+1)->nxt: last read t-1 ph2 (bb), drained there.
//   ph2 stage A-k0(t+2)->cur-A-kk0: all kk0-A reads (ph0+ph1) drained before
//       ph1's barrier. reads cur kk1: staged t-1 ph0/ph1, guaranteed by
//       end-of-(t-1) vmcnt(4) + barrier.
//   ph3 stage B-k0(t+2)->cur-B-kk0: bb kk0 reads drained in ph0.
//   tile end: vmcnt(4) -> t+1 fully landed, t+2-k0 (4 loads) stays in flight.
template <int I0>
__device__ __forceinline__ void mfma_quad(const bf16x8 (&bb)[4], bf16x8 a,
                                          floatx4 (&acc)[8][4]) {
#pragma unroll
  for (int j = 0; j < 4; ++j)
    acc[I0][j] =
        __builtin_amdgcn_mfma_f32_16x16x32_bf16(bb[j], a, acc[I0][j], 0, 0, 0);
}

// 8-read phase: af rows I0..I0+3 from Ab, bb[0..3] from Bb.
// Issue order pinned: {af0, bb0-3} | af1 | af2 | af3 (SB0-separated) so the
// counted ladder lgkm(3/2/1/0) gates exactly {quad0 operands}/af1/af2/af3.
template <int I0>
__device__ __forceinline__ void phaseA(const char* Ab, const char* Bb,
                                       bf16x8 (&bb)[4], floatx4 (&acc)[8][4]) {
  bf16x8 af0 = *(const bf16x8*)(Ab + (I0 + 0) * 1024);
  bb[0] = *(const bf16x8*)(Bb);
  bb[1] = *(const bf16x8*)(Bb + 1024);
  bb[2] = *(const bf16x8*)(Bb + 2048);
  bb[3] = *(const bf16x8*)(Bb + 3072);
  SB0;
  bf16x8 af1 = *(const bf16x8*)(Ab + (I0 + 1) * 1024);
  SB0;
  bf16x8 af2 = *(const bf16x8*)(Ab + (I0 + 2) * 1024);
  SB0;
  bf16x8 af3 = *(const bf16x8*)(Ab + (I0 + 3) * 1024);
  __builtin_amdgcn_s_setprio(1);
  LGKM(3);
  mfma_quad<I0 + 0>(bb, af0, acc);
  LGKM(2);
  mfma_quad<I0 + 1>(bb, af1, acc);
  LGKM(1);
  mfma_quad<I0 + 2>(bb, af2, acc);
  LGKM(0);
  mfma_quad<I0 + 3>(bb, af3, acc);
  __builtin_amdgcn_s_setprio(0);
}

// 4-read phase: af rows I0..I0+3, bb held live from the preceding phaseA.
template <int I0>
__device__ __forceinline__ void phaseB(const char* Ab, const bf16x8 (&bb)[4],
                                       floatx4 (&acc)[8][4]) {
  bf16x8 af0 = *(const bf16x8*)(Ab + (I0 + 0) * 1024);
  SB0;
  bf16x8 af1 = *(const bf16x8*)(Ab + (I0 + 1) * 1024);
  SB0;
  bf16x8 af2 = *(const bf16x8*)(Ab + (I0 + 2) * 1024);
  SB0;
  bf16x8 af3 = *(const bf16x8*)(Ab + (I0 + 3) * 1024);
  __builtin_amdgcn_s_setprio(1);
  LGKM(3);
  mfma_quad<I0 + 0>(bb, af0, acc);
  LGKM(2);
  mfma_quad<I0 + 1>(bb, af1, acc);
  LGKM(1);
  mfma_quad<I0 + 2>(bb, af2, acc);
  LGKM(0);
  mfma_quad<I0 + 3>(bb, af3, acc);
  __builtin_amdgcn_s_setprio(0);
}

template <int CURB>
__device__ __forceinline__ void ktile(int t, int NT, int K,
                                      const bf16_t* gA, const bf16_t* gB,
                                      char* lds, int tid, int aoff0, int boff0,
                                      floatx4 (&acc)[8][4]) {
  constexpr int curO = CURB * 65536;
  constexpr int nxtO = (CURB ^ 1) * 65536;
  bf16x8 bb[4];
  const char* Ab0 = lds + curO + aoff0;            // A kk0
  const char* Ab1 = lds + curO + 16384 + aoff0;    // A kk1
  const char* Bb0 = lds + curO + 32768 + boff0;    // B kk0
  const char* Bb1 = lds + curO + 49152 + boff0;    // B kk1

  // ph0: m0-3 x kk0 | stage A-k1(t+1) -> nxt
  if (t + 1 < NT)
    stage_half(gA + (size_t)(t + 1) * 64 + 32, K, lds + nxtO + 16384, tid);
  phaseA<0>(Ab0, Bb0, bb, acc);
  __builtin_amdgcn_s_barrier();
  SB0;

  // ph1: m4-7 x kk0 | stage B-k1(t+1) -> nxt
  if (t + 1 < NT)
    stage_half(gB + (size_t)(t + 1) * 64 + 32, K, lds + nxtO + 49152, tid);
  phaseB<4>(Ab0, bb, acc);
  __builtin_amdgcn_s_barrier();
  SB0;

  // ph2: m0-3 x kk1 | stage A-k0(t+2) -> cur (kk0-A fully retired)
  if (t + 2 < NT)
    stage_half(gA + (size_t)(t + 2) * 64, K, lds + curO, tid);
  phaseA<0>(Ab1, Bb1, bb, acc);
  __builtin_amdgcn_s_barrier();
  SB0;

  // ph3: m4-7 x kk1 | stage B-k0(t+2) -> cur
  if (t + 2 < NT)
    stage_half(gB + (size_t)(t + 2) * 64, K, lds + curO + 32768, tid);
  phaseB<4>(Ab1, bb, acc);
  // counted vmcnt: never 0 in steady state. 4 loads = t+2's k0 halves.
  if (t + 2 < NT) {
    asm volatile("s_waitcnt vmcnt(4)" ::: "memory");
  } else if (t + 1 < NT) {
    asm volatile("s_waitcnt vmcnt(0)" ::: "memory");
  }
  SB0;
  __builtin_amdgcn_s_barrier();
  SB0;
}

template <int EPI>
__global__ __launch_bounds__(512, 2) void gemm256(
    const bf16_t* __restrict__ A, const bf16_t* __restrict__ Bt,
    const float* __restrict__ bias, void* __restrict__ Cout, int N, int K) {
  extern __shared__ char lds[];
  const int tid = threadIdx.x;
  const int lane = tid & 63;
  const int wave = tid >> 6;
  const int wm = (wave >> 2) * 128;  // 2 M-waves
  const int wn = (wave & 3) * 64;    // 4 N-waves
  const int l15 = lane & 15;
  // swizzled ds_read slot: (logical slot lane>>4) ^ ((row>>1)&3)
  const int kqs = ((lane >> 4) ^ ((lane >> 1) & 3)) << 4;
  const int aoff0 = (wm + l15) * 64 + kqs;
  const int bofB0 = (wn + l15) * 64 + kqs;

  // XCD-aware bijective swizzle (nwg % 8 == 0 for all our grids)
  const int gx = gridDim.x;
  int id = blockIdx.y * gx + blockIdx.x;
  const int cpx = (gx * (int)gridDim.y) >> 3;
  id = (id & 7) * cpx + (id >> 3);
  const int bm = (id / gx) * 256;
  const int bn = (id % gx) * 256;

  // staging source: row tid>>2 (+128 for 2nd issue), inverse-swizzled k-slot
  const int srow = tid >> 2;
  const int ss8 = ((tid & 3) ^ ((tid >> 3) & 3)) * 8;
  const bf16_t* gA = A + (size_t)(bm + srow) * K + ss8;
  const bf16_t* gB = Bt + (size_t)(bn + srow) * K + ss8;

  const int NT = K >> 6;  // 32 or 64, always even

  floatx4 acc[8][4] = {};

  // ---- prologue: tile0 (4 halves) + tile1 k0 halves; vmcnt(4) leaves t1-k0
  stage_half(gA, K, lds + 0, tid);
  stage_half(gA + 32, K, lds + 16384, tid);
  stage_half(gB, K, lds + 32768, tid);
  stage_half(gB + 32, K, lds + 49152, tid);
  stage_half(gA + 64, K, lds + 65536, tid);
  stage_half(gB + 64, K, lds + 65536 + 32768, tid);
  asm volatile("s_waitcnt vmcnt(4)" ::: "memory");
  __builtin_amdgcn_s_barrier();
  SB0;

  for (int t = 0; t < NT; t += 2) {
    ktile<0>(t, NT, K, gA, gB, lds, tid, aoff0, bofB0, acc);
    ktile<1>(t + 1, NT, K, gA, gB, lds, tid, aoff0, bofB0, acc);
  }

  // epilogue (swapped-operand layout): acc[i][j] lane l reg r =
  //   C[bm + wm + i*16 + (l&15)][bn + wn + j*16 + (l>>4)*4 + r]
  const int kq4 = lane >> 4;
  const int row00 = bm + wm + l15;
  const int colq = bn + wn + kq4 * 4;
  float4 b4[4];
#pragma unroll
  for (int j = 0; j < 4; ++j) b4[j] = *(const float4*)&bias[colq + j * 16];
#pragma unroll
  for (int i = 0; i < 8; ++i) {
    const size_t rbase = (size_t)(row00 + i * 16) * N;
#pragma unroll
    for (int j = 0; j < 4; ++j) {
      float x0 = acc[i][j][0] + b4[j].x;
      float x1 = acc[i][j][1] + b4[j].y;
      float x2 = acc[i][j][2] + b4[j].z;
      float x3 = acc[i][j][3] + b4[j].w;
      if (EPI == 0) {
        x0 = fmaxf(x0, 0.f);
        x1 = fmaxf(x1, 0.f);
        x2 = fmaxf(x2, 0.f);
        x3 = fmaxf(x3, 0.f);
        bf16x4 o;
        o[0] = (bf16_t)x0; o[1] = (bf16_t)x1; o[2] = (bf16_t)x2; o[3] = (bf16_t)x3;
        *(bf16x4*)((bf16_t*)Cout + rbase + colq + j * 16) = o;
      } else {
        float4 o = make_float4(x0, x1, x2, x3);
        *(float4*)((float*)Cout + rbase + colq + j * 16) = o;
      }
    }
  }
}

// ---------------------------------------------------------------------------
extern "C" void kernel_launch(void* const* d_in, const int* in_sizes, int n_in,
                              void* d_out, int out_size, void* d_ws, size_t ws_size,
                              hipStream_t stream) {
  const float* x = (const float*)d_in[0];
  const float *Mm[4], *uu[4], *vv[4], *ee[4];
  for (int i = 0; i < 4; ++i) {
    Mm[i] = (const float*)d_in[1 + 4 * i];
    uu[i] = (const float*)d_in[2 + 4 * i];
    vv[i] = (const float*)d_in[3 + 4 * i];
    ee[i] = (const float*)d_in[4 + 4 * i];
  }

  // workspace layout (≈224 MiB):
  //   Wt0 [4096,2048] bf16 | Wt1 [4096,4096] | Wt2 [4096,4096] | Wt3 [2048,4096]
  //   bias0..3 fp32 | hA (8192x4096 bf16) | hB (8192x4096 bf16)
  char* ws = (char*)d_ws;
  bf16_t* Wt0 = (bf16_t*)ws;
  bf16_t* Wt1 = (bf16_t*)(ws + 16777216);
  bf16_t* Wt2 = (bf16_t*)(ws + 16777216 + 33554432);
  bf16_t* Wt3 = (bf16_t*)(ws + 16777216 + 2u * 33554432);
  char* bptr = ws + 2u * 16777216 + 2u * 33554432;
  float* bias0 = (float*)(bptr);
  float* bias1 = (float*)(bptr + 16384);
  float* bias2 = (float*)(bptr + 32768);
  float* bias3 = (float*)(bptr + 49152);
  char* act = bptr + 65536;
  bf16_t* hA = (bf16_t*)act;
  bf16_t* hB = (bf16_t*)(act + 67108864);
  bf16_t* xb = (bf16_t*)d_out;  // dead until final GEMM overwrites d_out

  static bool attr_set = false;
  if (!attr_set) {
    (void)hipFuncSetAttribute(reinterpret_cast<const void*>(&gemm256<0>),
                              hipFuncAttributeMaxDynamicSharedMemorySize, 131072);
    (void)hipFuncSetAttribute(reinterpret_cast<const void*>(&gemm256<1>),
                              hipFuncAttributeMaxDynamicSharedMemorySize, 131072);
    attr_set = true;
  }

  // --- prep ---
  cvt_to_bf16<<<16384, 256, 0, stream>>>((const float4*)x, (bf16x4*)xb,
                                         8192 * 2048 / 4);
  prep_wt<<<dim3(4096 / 32, 2048 / 32), dim3(32, 8), 0, stream>>>(
      Mm[0], uu[0], vv[0], ee[0], Wt0, 2048, 4096);
  prep_wt<<<dim3(4096 / 32, 4096 / 32), dim3(32, 8), 0, stream>>>(
      Mm[1], uu[1], vv[1], ee[1], Wt1, 4096, 4096);
  prep_wt<<<dim3(4096 / 32, 4096 / 32), dim3(32, 8), 0, stream>>>(
      Mm[2], uu[2], vv[2], ee[2], Wt2, 4096, 4096);
  prep_wt<<<dim3(2048 / 32, 4096 / 32), dim3(32, 8), 0, stream>>>(
      Mm[3], uu[3], vv[3], ee[3], Wt3, 4096, 2048);
  BiasArgs ba;
  for (int i = 0; i < 4; ++i) {
    ba.M[i] = Mm[i]; ba.u[i] = uu[i]; ba.v[i] = vv[i]; ba.e[i] = ee[i];
  }
  ba.b[0] = bias0; ba.b[1] = bias1; ba.b[2] = bias2; ba.b[3] = bias3;
  prep_bias_all<<<56, 256, 0, stream>>>(ba);

  // --- chained GEMMs: 256^2, 1-barrier phases + counted lgkm ladder ---
  gemm256<0><<<dim3(16, 32), 512, 131072, stream>>>(xb, Wt0, bias0, hA, 4096, 2048);
  gemm256<0><<<dim3(16, 32), 512, 131072, stream>>>(hA, Wt1, bias1, hB, 4096, 4096);
  gemm256<0><<<dim3(16, 32), 512, 131072, stream>>>(hB, Wt2, bias2, hA, 4096, 4096);
  gemm256<1><<<dim3(8, 32), 512, 131072, stream>>>(hA, Wt3, bias3, d_out, 2048, 4096);
}